// Round 9
// baseline (6852.033 us; speedup 1.0000x reference)
//
#include <hip/hip_runtime.h>

typedef __attribute__((ext_vector_type(4))) float f32x4;
typedef __attribute__((ext_vector_type(4))) int   i32x4;
typedef __attribute__((ext_vector_type(8))) short s16x8;

#define MFMA16(a, b, c)  __builtin_amdgcn_mfma_f32_16x16x32_bf16((a), (b), (c), 0, 0, 0)
#define MFMAI8(a, b, c)  __builtin_amdgcn_mfma_i32_16x16x64_i8((a), (b), (c), 0, 0, 0)

#define QINV (1.0f / 252.0f)

// ---------- bf16 helpers (RNE) ----------
__device__ inline unsigned short f2bf(float f) {
    unsigned int u = __float_as_uint(f);
    return (unsigned short)((u + 0x7FFFu + ((u >> 16) & 1u)) >> 16);
}
__device__ inline float bf2f(unsigned short b) {
    return __uint_as_float(((unsigned int)b) << 16);
}

// ---------- pack W [K][1024] f32 -> THREE bf16 levels (W_in path) ----------
__global__ __launch_bounds__(256) void k_pack3(const float* __restrict__ W,
                                               unsigned short* __restrict__ L1,
                                               unsigned short* __restrict__ L2,
                                               unsigned short* __restrict__ L3,
                                               int K) {
    int idx = blockIdx.x * 256 + threadIdx.x;
    if (idx >= K * 1024) return;
    int k = idx >> 10;
    int n = idx & 1023;
    float x = W[idx];
    unsigned short h1 = f2bf(x);  float r1 = x - bf2f(h1);
    unsigned short h2 = f2bf(r1); float r2 = r1 - bf2f(h2);
    unsigned short h3 = f2bf(r2);
    size_t o = ((size_t)(k >> 5) << 15) + ((size_t)n << 5) + (k & 31);
    L1[o] = h1; L2[o] = h2; L3[o] = h3;
}

// ---------- per-column max|W_rec| -> t1[n] = max/126 ----------
__global__ __launch_bounds__(256) void k_colmax(const float* __restrict__ W,
                                                float* __restrict__ t1) {
    __shared__ float red[256];
    int n = blockIdx.x;
    float m = 0.f;
    for (int k = threadIdx.x; k < 1024; k += 256)
        m = fmaxf(m, fabsf(W[(size_t)k * 1024 + n]));
    red[threadIdx.x] = m;
    __syncthreads();
    for (int s = 128; s > 0; s >>= 1) {
        if (threadIdx.x < s) red[threadIdx.x] = fmaxf(red[threadIdx.x], red[threadIdx.x + s]);
        __syncthreads();
    }
    if (threadIdx.x == 0) t1[n] = fmaxf(red[0], 1e-30f) * (1.0f / 126.0f);
}

// ---------- pack W_rec -> 3 i8 digits, interleaved [kt][n][lvl][64] ----------
__global__ __launch_bounds__(256) void k_packq(const float* __restrict__ W,
                                               const float* __restrict__ t1a,
                                               signed char* __restrict__ Q) {
    int idx = blockIdx.x * 256 + threadIdx.x;   // k*1024 + n
    int k = idx >> 10;
    int n = idx & 1023;
    float x = W[idx];
    float T1 = t1a[n];
    float T2 = T1 * QINV;
    float T3 = T2 * QINV;
    float q1 = rintf(x / T1);  float r1 = fmaf(-q1, T1, x);
    float q2 = rintf(r1 / T2); float r2 = fmaf(-q2, T2, r1);
    float q3 = rintf(r2 / T3);
    size_t o = ((size_t)((k >> 6) * 1024 + n)) * 192 + (k & 63);
    Q[o]       = (signed char)(int)q1;
    Q[o + 64]  = (signed char)(int)q2;
    Q[o + 128] = (signed char)(int)q3;
}

// ---------- main: 128 blocks x 16 rows, 512 thr (8 waves, 2 waves/SIMD) ----------
// Wave w owns cols {w*64..+64} (g=0) and {512+w*64..+64} (g=1). Per kt, both
// groups interleave: 24 MFMAs consume flattened frag stream J = kt*24 + j,
// j = g*12+nt*3+lvl, through an 8-deep register ring (32 VGPR). ONE coherent
// 3MB sweep per step (R4's proven L2-friendly order). Budget: 96 AGPR acc +
// ~130 VGPR <= 256 cap -> no spill (the R8 failure mode).
#define FSTR 770
#define LDS_SPK0   0        // i8 [16][1024] XOR-swizzled, buf0
#define LDS_SPK1   16384    // buf1
#define LDS_FUSED  32768    // f32 [16][770] (phases A/B only, dies after B)
#define LDS_DEC    32768    // f32[1024] (written after phase B)
#define LDS_FRQ    36864
#define LDS_T1     40960
#define LDS_BASE2  45056    // f32 [16][1028]
#define LDS_TOTAL  110848
__global__ __launch_bounds__(512, 2) void k_main(const float* __restrict__ fused,
                                                 const unsigned short* __restrict__ Wi1,
                                                 const unsigned short* __restrict__ Wi2,
                                                 const unsigned short* __restrict__ Wi3,
                                                 const float* __restrict__ b_in,
                                                 const signed char* __restrict__ WrQ,
                                                 const float* __restrict__ t1a,
                                                 const float* __restrict__ b_rec,
                                                 const float* __restrict__ rdec,
                                                 const float* __restrict__ rfrq,
                                                 const float* __restrict__ W_out,
                                                 const float* __restrict__ b_out,
                                                 float* __restrict__ out) {
    extern __shared__ __align__(16) char smem[];
    const int tid = threadIdx.x;
    const int w = tid >> 6, lane = tid & 63;
    const int llo = lane & 15, lhi = lane >> 4;
    const int r0 = blockIdx.x * 16;

    // ---- phase A: stage fused[r0:r0+16][0:768] -> LDS ----
    float* fl = (float*)(smem + LDS_FUSED);
    for (int i = tid; i < 16 * 768; i += 512) {
        int rr = i / 768, cc = i - rr * 768;
        fl[rr * FSTR + cc] = fused[(size_t)(r0 + rr) * 768 + cc];
    }
    __syncthreads();

    // ---- phase B: base = fused @ W_in + b_in (3x3-level bf16, 6 passes) ----
    f32x4 bacc[2][4] = {};
    for (int kt = 0; kt < 24; ++kt) {
        const float* ap = fl + llo * FSTR + kt * 32 + lhi * 8;
        s16x8 a1v, a2v, a3v;
#pragma unroll
        for (int j = 0; j < 8; ++j) {
            float x = ap[j];
            unsigned short h1 = f2bf(x);  float r1 = x - bf2f(h1);
            unsigned short h2 = f2bf(r1); float r2 = r1 - bf2f(h2);
            a1v[j] = (short)h1; a2v[j] = (short)h2; a3v[j] = (short)f2bf(r2);
        }
#pragma unroll
        for (int g = 0; g < 2; ++g) {
#pragma unroll
            for (int nt = 0; nt < 4; ++nt) {
                int c = g * 512 + w * 64 + nt * 16 + llo;
                size_t boff = ((size_t)(kt * 1024 + c) << 5) + lhi * 8;
                s16x8 b1 = *(const s16x8*)&Wi1[boff];
                s16x8 b2 = *(const s16x8*)&Wi2[boff];
                s16x8 b3 = *(const s16x8*)&Wi3[boff];
                bacc[g][nt] = MFMA16(a1v, b1, bacc[g][nt]);
                bacc[g][nt] = MFMA16(a1v, b2, bacc[g][nt]);
                bacc[g][nt] = MFMA16(a2v, b1, bacc[g][nt]);
                bacc[g][nt] = MFMA16(a2v, b2, bacc[g][nt]);
                bacc[g][nt] = MFMA16(a1v, b3, bacc[g][nt]);
                bacc[g][nt] = MFMA16(a3v, b1, bacc[g][nt]);
            }
        }
    }
    __syncthreads();   // fused dead; region becomes params/base2

    // ---- params ----
    float* ldsDec = (float*)(smem + LDS_DEC);
    float* ldsFrq = (float*)(smem + LDS_FRQ);
    float* ldsT1  = (float*)(smem + LDS_T1);
    for (int c = tid; c < 1024; c += 512) {
        ldsDec[c] = (float)(0.55 + 0.4 / (1.0 + exp(-(double)rdec[c])));
        ldsFrq[c] = (float)(0.10 + 0.9 / (1.0 + exp(-(double)rfrq[c])));
        ldsT1[c]  = t1a[c];
    }

    // ---- base2 -> LDS; inline t=0; spikes(0) -> SPK0 ----
    float mem[2][4][4], res[2][4][4];
    unsigned int pooled_pk[2][4] = {};
    float* b2 = (float*)(smem + LDS_BASE2);
#pragma unroll
    for (int g = 0; g < 2; ++g) {
#pragma unroll
        for (int nt = 0; nt < 4; ++nt) {
            int c = g * 512 + w * 64 + nt * 16 + llo;
            float bb = b_in[c];
            float brv = b_rec[c];
#pragma unroll
            for (int fr = 0; fr < 4; ++fr) {
                int row = lhi * 4 + fr;
                float b0 = __fadd_rn(bacc[g][nt][fr], bb);
                b2[row * 1028 + c] = __fadd_rn(b0, brv);
                float m_ = __fadd_rn(0.f, b0);
                int s = (m_ > 1.0f) ? 1 : 0;
                res[g][nt][fr] = 0.f;
                mem[g][nt][fr] = __fadd_rn(m_, -(float)s);
                pooled_pk[g][nt] += (unsigned int)s << (8 * fr);
                *(unsigned char*)(smem + LDS_SPK0 + ((row * 1024 + c) ^ ((row & 7) << 4))) =
                    (unsigned char)s;
            }
        }
    }
    __syncthreads();

    // ---- phase C: steps 1..31 ----
    const int ax = (llo & 7) << 4;
    const signed char* bpg0 = WrQ + ((size_t)(w * 64 + llo)) * 192 + lhi * 16;
    const signed char* bpg1 = WrQ + ((size_t)(512 + w * 64 + llo)) * 192 + lhi * 16;
    for (int t = 1; t < 32; ++t) {
        const char* ab = smem + ((t - 1) & 1) * 16384 + llo * 1024;
        char* wb = smem + (t & 1) * 16384;

        i32x4 acc[2][4][3] = {};
        i32x4 fb[8];
        // prologue: frags J=0..7 (all kt=0, g=0: nt=J/3, lvl=J%3)
#pragma unroll
        for (int j = 0; j < 8; ++j)
            fb[j] = *(const i32x4*)(bpg0 + (j / 3) * 3072 + (j % 3) * 64);
        i32x4 Acur = *(const i32x4*)(ab + ((lhi * 16) ^ ax));
        i32x4 Anx = Acur;
#pragma unroll
        for (int kt = 0; kt < 16; ++kt) {
#pragma unroll
            for (int j = 0; j < 24; ++j) {
                if (j == 0 && kt < 15)
                    Anx = *(const i32x4*)(ab + (((kt + 1) * 64 + lhi * 16) ^ ax));
                const int J = kt * 24 + j;
                const int slot = J & 7;
                i32x4 B = fb[slot];
                const int Jn = J + 8;
                if (Jn < 384) {
                    const int ktn = Jn / 24, jn = Jn % 24;
                    const int gn = jn / 12, rn = jn % 12, ntn = rn / 3, lvn = rn % 3;
                    const signed char* bp = gn ? bpg1 : bpg0;
                    fb[slot] = *(const i32x4*)(bp + (size_t)ktn * 196608 + ntn * 3072 + lvn * 64);
                }
                const int g = j / 12, r = j % 12, nt = r / 3, lvl = r % 3;
                acc[g][nt][lvl] = MFMAI8(Acur, B, acc[g][nt][lvl]);
            }
            Acur = Anx;
        }

        // state update (both groups)
#pragma unroll
        for (int g = 0; g < 2; ++g) {
#pragma unroll
            for (int nt = 0; nt < 4; ++nt) {
                int c = g * 512 + w * 64 + nt * 16 + llo;
                float dcc = ldsDec[c], fqc = ldsFrq[c], t1c = ldsT1[c];
#pragma unroll
                for (int fr = 0; fr < 4; ++fr) {
                    int row = lhi * 4 + fr;
                    float s3 = (float)acc[g][nt][2][fr];
                    float s2 = fmaf(s3, QINV, (float)acc[g][nt][1][fr]);
                    float rec = __fmul_rn(fmaf(s2, QINV, (float)acc[g][nt][0][fr]), t1c);
                    float drive = __fadd_rn(b2[row * 1028 + c], rec);
                    float rnew = __fadd_rn(__fmul_rn(dcc, res[g][nt][fr]),
                                           __fmul_rn(fqc, mem[g][nt][fr]));
                    float tt = __fadd_rn(__fmul_rn(dcc, mem[g][nt][fr]), drive);
                    float m_ = __fadd_rn(tt, -rnew);
                    int s = (m_ > 1.0f) ? 1 : 0;
                    res[g][nt][fr] = rnew;
                    mem[g][nt][fr] = __fadd_rn(m_, -(float)s);
                    pooled_pk[g][nt] += (unsigned int)s << (8 * fr);
                    *(unsigned char*)(wb + ((row * 1024 + c) ^ ((row & 7) << 4))) =
                        (unsigned char)s;
                }
            }
        }
        __syncthreads();
    }

    // ---- phase D: pooled/32 -> LDS (base2 region, dead), f64 dot W_out ----
    float* plds = (float*)(smem + LDS_BASE2);
#pragma unroll
    for (int g = 0; g < 2; ++g)
#pragma unroll
        for (int nt = 0; nt < 4; ++nt) {
            int c = g * 512 + w * 64 + nt * 16 + llo;
#pragma unroll
            for (int fr = 0; fr < 4; ++fr)
                plds[(lhi * 4 + fr) * 1028 + c] =
                    (float)((pooled_pk[g][nt] >> (8 * fr)) & 255u) * 0.03125f;
        }
    __syncthreads();
    if (tid < 256) {
        int row = tid >> 4, o = tid & 15;
        double s = 0.0;
        for (int h = 0; h < 1024; ++h)
            s += (double)plds[row * 1028 + h] * (double)W_out[h * 16 + o];
        out[(size_t)(r0 + row) * 16 + o] = __fadd_rn((float)s, b_out[o]);
    }
}

extern "C" void kernel_launch(void* const* d_in, const int* in_sizes, int n_in,
                              void* d_out, int out_size, void* d_ws, size_t ws_size,
                              hipStream_t stream) {
    const float* fused = (const float*)d_in[0];
    const float* W_in  = (const float*)d_in[1];
    const float* b_in  = (const float*)d_in[2];
    const float* W_rec = (const float*)d_in[3];
    const float* b_rec = (const float*)d_in[4];
    const float* W_out = (const float*)d_in[5];
    const float* b_out = (const float*)d_in[6];
    const float* rdec  = (const float*)d_in[7];
    const float* rfrq  = (const float*)d_in[8];

    // ws: WrQ 3MB | t1 4KB | Wi1/2/3 4.5MB  (total ~7.75MB)
    char* ws = (char*)d_ws;
    signed char*    WrQ = (signed char*)(ws);
    float*          t1a = (float*)(ws + (3u << 20));
    unsigned short* Wi1 = (unsigned short*)(ws + (3u << 20) + (1u << 18));
    unsigned short* Wi2 = (unsigned short*)(ws + (3u << 20) + (1u << 18) + (3u << 19));
    unsigned short* Wi3 = (unsigned short*)(ws + (3u << 20) + (1u << 18) + (6u << 19));
    float* out = (float*)d_out;

    hipFuncSetAttribute((const void*)k_main,
                        hipFuncAttributeMaxDynamicSharedMemorySize, LDS_TOTAL);

    hipLaunchKernelGGL(k_colmax, dim3(1024), dim3(256), 0, stream, W_rec, t1a);
    hipLaunchKernelGGL(k_packq, dim3(4096), dim3(256), 0, stream, W_rec, t1a, WrQ);
    hipLaunchKernelGGL(k_pack3, dim3(3072), dim3(256), 0, stream, W_in, Wi1, Wi2, Wi3, 768);
    hipLaunchKernelGGL(k_main, dim3(128), dim3(512), LDS_TOTAL, stream,
                       fused, Wi1, Wi2, Wi3, b_in, WrQ, t1a, b_rec,
                       rdec, rfrq, W_out, b_out, out);
}

// Round 10
// 3884.213 us; speedup vs baseline: 1.7641x; 1.7641x over previous
//
#include <hip/hip_runtime.h>

typedef __attribute__((ext_vector_type(4))) float f32x4;
typedef __attribute__((ext_vector_type(4))) int   i32x4;
typedef __attribute__((ext_vector_type(8))) short s16x8;

#define MFMA16(a, b, c)  __builtin_amdgcn_mfma_f32_16x16x32_bf16((a), (b), (c), 0, 0, 0)
#define MFMAI8(a, b, c)  __builtin_amdgcn_mfma_i32_16x16x64_i8((a), (b), (c), 0, 0, 0)

#define QINV (1.0f / 252.0f)

// global->LDS async copy, 16B/lane. Dest must be wave-uniform base (+lane*16 implicit).
typedef __attribute__((address_space(3))) unsigned int lds_uint;
typedef const __attribute__((address_space(1))) unsigned int glob_uint;
__device__ __forceinline__ void glds16(const void* g, void* l) {
    __builtin_amdgcn_global_load_lds((glob_uint*)g, (lds_uint*)l, 16, 0, 0);
}

// ---------- bf16 helpers (RNE) ----------
__device__ inline unsigned short f2bf(float f) {
    unsigned int u = __float_as_uint(f);
    return (unsigned short)((u + 0x7FFFu + ((u >> 16) & 1u)) >> 16);
}
__device__ inline float bf2f(unsigned short b) {
    return __uint_as_float(((unsigned int)b) << 16);
}

// ---------- pack W [K][1024] f32 -> THREE bf16 levels (W_in path) ----------
__global__ __launch_bounds__(256) void k_pack3(const float* __restrict__ W,
                                               unsigned short* __restrict__ L1,
                                               unsigned short* __restrict__ L2,
                                               unsigned short* __restrict__ L3,
                                               int K) {
    int idx = blockIdx.x * 256 + threadIdx.x;
    if (idx >= K * 1024) return;
    int k = idx >> 10;
    int n = idx & 1023;
    float x = W[idx];
    unsigned short h1 = f2bf(x);  float r1 = x - bf2f(h1);
    unsigned short h2 = f2bf(r1); float r2 = r1 - bf2f(h2);
    unsigned short h3 = f2bf(r2);
    size_t o = ((size_t)(k >> 5) << 15) + ((size_t)n << 5) + (k & 31);
    L1[o] = h1; L2[o] = h2; L3[o] = h3;
}

// ---------- per-column max|W_rec| -> t1[n] = max/126 ----------
__global__ __launch_bounds__(256) void k_colmax(const float* __restrict__ W,
                                                float* __restrict__ t1) {
    __shared__ float red[256];
    int n = blockIdx.x;
    float m = 0.f;
    for (int k = threadIdx.x; k < 1024; k += 256)
        m = fmaxf(m, fabsf(W[(size_t)k * 1024 + n]));
    red[threadIdx.x] = m;
    __syncthreads();
    for (int s = 128; s > 0; s >>= 1) {
        if (threadIdx.x < s) red[threadIdx.x] = fmaxf(red[threadIdx.x], red[threadIdx.x + s]);
        __syncthreads();
    }
    if (threadIdx.x == 0) t1[n] = fmaxf(red[0], 1e-30f) * (1.0f / 126.0f);
}

// ---------- pack W_rec -> 3 i8 digits, interleaved [kt][n][lvl][64] ----------
__global__ __launch_bounds__(256) void k_packq(const float* __restrict__ W,
                                               const float* __restrict__ t1a,
                                               signed char* __restrict__ Q) {
    int idx = blockIdx.x * 256 + threadIdx.x;   // k*1024 + n
    int k = idx >> 10;
    int n = idx & 1023;
    float x = W[idx];
    float T1 = t1a[n];
    float T2 = T1 * QINV;
    float T3 = T2 * QINV;
    float q1 = rintf(x / T1);  float r1 = fmaf(-q1, T1, x);
    float q2 = rintf(r1 / T2); float r2 = fmaf(-q2, T2, r1);
    float q3 = rintf(r2 / T3);
    size_t o = ((size_t)((k >> 6) * 1024 + n)) * 192 + (k & 63);
    Q[o]       = (signed char)(int)q1;
    Q[o + 64]  = (signed char)(int)q2;
    Q[o + 128] = (signed char)(int)q3;
}

// ---------- main: 128 blocks x 16 rows, 1024 thr (R4 structure) ----------
// Phase C B-path: per (kt,nt) chunk = 3 frags staged into a WAVE-PRIVATE
// 2-slot LDS ring by global_load_lds (no VGPR cost, async). Counted
// vmcnt(3) is exact: phase C has no other VMEM ops. ds_read at lane*16 ->
// conflict-free. Same sums/order as R4 -> bit-identical output.
#define FSTR 770
#define LDS_SPK0   0        // i8 [16][1024] XOR-swizzled, buf0
#define LDS_SPK1   16384    // buf1
#define LDS_DEC    32768    // f32[1024]
#define LDS_FRQ    36864
#define LDS_T1     40960
#define LDS_RING   49152    // 16 waves x 6144 B (2 slots x 3 KB) -> 147456
#define LDS_FUSED  49152    // f32 [16][770] (phases A/B only, dies after B)
#define LDS_PLDS   49152    // f32 [16][1028] (phase D)
#define LDS_TOTAL  147456
__global__ __launch_bounds__(1024, 1) void k_main(const float* __restrict__ fused,
                                                  const unsigned short* __restrict__ Wi1,
                                                  const unsigned short* __restrict__ Wi2,
                                                  const unsigned short* __restrict__ Wi3,
                                                  const float* __restrict__ b_in,
                                                  const signed char* __restrict__ WrQ,
                                                  const float* __restrict__ t1a,
                                                  const float* __restrict__ b_rec,
                                                  const float* __restrict__ rdec,
                                                  const float* __restrict__ rfrq,
                                                  const float* __restrict__ W_out,
                                                  const float* __restrict__ b_out,
                                                  float* __restrict__ out) {
    extern __shared__ __align__(16) char smem[];
    const int tid = threadIdx.x;
    const int w = tid >> 6, lane = tid & 63;
    const int llo = lane & 15, lhi = lane >> 4;
    const int r0 = blockIdx.x * 16;

    // ---- phase A: stage fused[r0:r0+16][0:768] -> LDS ----
    float* fl = (float*)(smem + LDS_FUSED);
    for (int i = tid; i < 16 * 768; i += 1024) {
        int rr = i / 768, cc = i - rr * 768;
        fl[rr * FSTR + cc] = fused[(size_t)(r0 + rr) * 768 + cc];
    }
    __syncthreads();

    // ---- phase B: base = fused @ W_in + b_in (3x3-level bf16, 6 passes) ----
    f32x4 bacc[4] = {};
    for (int kt = 0; kt < 24; ++kt) {
        const float* ap = fl + llo * FSTR + kt * 32 + lhi * 8;
        s16x8 a1v, a2v, a3v;
#pragma unroll
        for (int j = 0; j < 8; ++j) {
            float x = ap[j];
            unsigned short h1 = f2bf(x);  float r1 = x - bf2f(h1);
            unsigned short h2 = f2bf(r1); float r2 = r1 - bf2f(h2);
            a1v[j] = (short)h1; a2v[j] = (short)h2; a3v[j] = (short)f2bf(r2);
        }
#pragma unroll
        for (int nt = 0; nt < 4; ++nt) {
            int c = w * 64 + nt * 16 + llo;
            size_t boff = ((size_t)(kt * 1024 + c) << 5) + lhi * 8;
            s16x8 b1 = *(const s16x8*)&Wi1[boff];
            s16x8 b2 = *(const s16x8*)&Wi2[boff];
            s16x8 b3 = *(const s16x8*)&Wi3[boff];
            bacc[nt] = MFMA16(a1v, b1, bacc[nt]);
            bacc[nt] = MFMA16(a1v, b2, bacc[nt]);
            bacc[nt] = MFMA16(a2v, b1, bacc[nt]);
            bacc[nt] = MFMA16(a2v, b2, bacc[nt]);
            bacc[nt] = MFMA16(a1v, b3, bacc[nt]);
            bacc[nt] = MFMA16(a3v, b1, bacc[nt]);
        }
    }
    __syncthreads();   // fused dead

    // ---- params ----
    float* ldsDec = (float*)(smem + LDS_DEC);
    float* ldsFrq = (float*)(smem + LDS_FRQ);
    float* ldsT1  = (float*)(smem + LDS_T1);
    for (int c = tid; c < 1024; c += 1024) { }  // (no-op; kept simple below)
    {
        int c = tid;  // 1024 threads cover 1024 cols exactly
        ldsDec[c] = (float)(0.55 + 0.4 / (1.0 + exp(-(double)rdec[c])));
        ldsFrq[c] = (float)(0.10 + 0.9 / (1.0 + exp(-(double)rfrq[c])));
        ldsT1[c]  = t1a[c];
    }

    // ---- base2 in regs; inline t=0; spikes(0) -> SPK0 ----
    float base2[4][4];
    float mem[4][4], res[4][4];
    unsigned int pooled_pk[4] = {0, 0, 0, 0};
#pragma unroll
    for (int nt = 0; nt < 4; ++nt) {
        int c = w * 64 + nt * 16 + llo;
        float bb = b_in[c];
        float brv = b_rec[c];
#pragma unroll
        for (int fr = 0; fr < 4; ++fr) {
            int row = lhi * 4 + fr;
            float b0 = __fadd_rn(bacc[nt][fr], bb);
            base2[nt][fr] = __fadd_rn(b0, brv);
            float m_ = __fadd_rn(0.f, b0);
            int s = (m_ > 1.0f) ? 1 : 0;
            res[nt][fr] = 0.f;
            mem[nt][fr] = __fadd_rn(m_, -(float)s);
            pooled_pk[nt] += (unsigned int)s << (8 * fr);
            *(unsigned char*)(smem + LDS_SPK0 + ((row * 1024 + c) ^ ((row & 7) << 4))) =
                (unsigned char)s;
        }
    }
    __syncthreads();

    // ---- phase C: steps 1..31 ----
    const int ax = (llo & 7) << 4;
    // per-lane global base for this lane's B-frag bytes (nt=0, lvl=0, kt=0)
    const signed char* gb = WrQ + ((size_t)(w * 64 + llo)) * 192 + lhi * 16;
    char* ring = smem + LDS_RING + w * 6144;

    for (int t = 1; t < 32; ++t) {
        const char* ab = smem + ((t - 1) & 1) * 16384 + llo * 1024;
        char* wb = smem + (t & 1) * 16384;

        i32x4 acc[4][3] = {};
        // prologue: stage chunk 0 (kt=0, nt=0) into slot 0
        glds16(gb,       ring);
        glds16(gb + 64,  ring + 1024);
        glds16(gb + 128, ring + 2048);

        i32x4 Af;
#pragma unroll 4
        for (int c = 0; c < 63; ++c) {
            const int kt = c >> 2, nt = c & 3;
            // stage chunk c+1 into the other slot
            {
                const int c2 = c + 1, kt2 = c2 >> 2, nt2 = c2 & 3;
                const signed char* s = gb + (size_t)kt2 * 196608 + nt2 * 3072;
                char* d = ring + (c2 & 1) * 3072;
                glds16(s,       d);
                glds16(s + 64,  d + 1024);
                glds16(s + 128, d + 2048);
            }
            asm volatile("s_waitcnt vmcnt(3)" ::: "memory");
            __builtin_amdgcn_sched_barrier(0);
            if (nt == 0)
                Af = *(const i32x4*)(ab + ((kt * 64 + lhi * 16) ^ ax));
            const char* d = ring + (c & 1) * 3072 + (size_t)lane * 16;
            i32x4 B1 = *(const i32x4*)(d);
            i32x4 B2 = *(const i32x4*)(d + 1024);
            i32x4 B3 = *(const i32x4*)(d + 2048);
            acc[nt][0] = MFMAI8(Af, B1, acc[nt][0]);
            acc[nt][1] = MFMAI8(Af, B2, acc[nt][1]);
            acc[nt][2] = MFMAI8(Af, B3, acc[nt][2]);
        }
        // epilogue: chunk 63 (kt=15, nt=3), slot 1
        {
            asm volatile("s_waitcnt vmcnt(0)" ::: "memory");
            __builtin_amdgcn_sched_barrier(0);
            const char* d = ring + 3072 + (size_t)lane * 16;
            i32x4 B1 = *(const i32x4*)(d);
            i32x4 B2 = *(const i32x4*)(d + 1024);
            i32x4 B3 = *(const i32x4*)(d + 2048);
            acc[3][0] = MFMAI8(Af, B1, acc[3][0]);
            acc[3][1] = MFMAI8(Af, B2, acc[3][1]);
            acc[3][2] = MFMAI8(Af, B3, acc[3][2]);
        }

        // state update (exact np op order)
#pragma unroll
        for (int nt = 0; nt < 4; ++nt) {
            int c = w * 64 + nt * 16 + llo;
            float dcc = ldsDec[c], fqc = ldsFrq[c], t1c = ldsT1[c];
#pragma unroll
            for (int fr = 0; fr < 4; ++fr) {
                int row = lhi * 4 + fr;
                float s3 = (float)acc[nt][2][fr];
                float s2 = fmaf(s3, QINV, (float)acc[nt][1][fr]);
                float rec = __fmul_rn(fmaf(s2, QINV, (float)acc[nt][0][fr]), t1c);
                float drive = __fadd_rn(base2[nt][fr], rec);
                float rnew = __fadd_rn(__fmul_rn(dcc, res[nt][fr]),
                                       __fmul_rn(fqc, mem[nt][fr]));
                float tt = __fadd_rn(__fmul_rn(dcc, mem[nt][fr]), drive);
                float m_ = __fadd_rn(tt, -rnew);
                int s = (m_ > 1.0f) ? 1 : 0;
                res[nt][fr] = rnew;
                mem[nt][fr] = __fadd_rn(m_, -(float)s);
                pooled_pk[nt] += (unsigned int)s << (8 * fr);
                *(unsigned char*)(wb + ((row * 1024 + c) ^ ((row & 7) << 4))) =
                    (unsigned char)s;
            }
        }
        __syncthreads();
    }

    // ---- phase D: pooled/32 -> LDS, f64 dot with W_out ----
    float* plds = (float*)(smem + LDS_PLDS);
#pragma unroll
    for (int nt = 0; nt < 4; ++nt) {
        int c = w * 64 + nt * 16 + llo;
#pragma unroll
        for (int fr = 0; fr < 4; ++fr)
            plds[(lhi * 4 + fr) * 1028 + c] =
                (float)((pooled_pk[nt] >> (8 * fr)) & 255u) * 0.03125f;
    }
    __syncthreads();
    if (tid < 256) {
        int row = tid >> 4, o = tid & 15;
        double s = 0.0;
        for (int h = 0; h < 1024; ++h)
            s += (double)plds[row * 1028 + h] * (double)W_out[h * 16 + o];
        out[(size_t)(r0 + row) * 16 + o] = __fadd_rn((float)s, b_out[o]);
    }
}

extern "C" void kernel_launch(void* const* d_in, const int* in_sizes, int n_in,
                              void* d_out, int out_size, void* d_ws, size_t ws_size,
                              hipStream_t stream) {
    const float* fused = (const float*)d_in[0];
    const float* W_in  = (const float*)d_in[1];
    const float* b_in  = (const float*)d_in[2];
    const float* W_rec = (const float*)d_in[3];
    const float* b_rec = (const float*)d_in[4];
    const float* W_out = (const float*)d_in[5];
    const float* b_out = (const float*)d_in[6];
    const float* rdec  = (const float*)d_in[7];
    const float* rfrq  = (const float*)d_in[8];

    // ws: WrQ 3MB | t1 4KB | Wi1/2/3 4.5MB  (total ~7.75MB)
    char* ws = (char*)d_ws;
    signed char*    WrQ = (signed char*)(ws);
    float*          t1a = (float*)(ws + (3u << 20));
    unsigned short* Wi1 = (unsigned short*)(ws + (3u << 20) + (1u << 18));
    unsigned short* Wi2 = (unsigned short*)(ws + (3u << 20) + (1u << 18) + (3u << 19));
    unsigned short* Wi3 = (unsigned short*)(ws + (3u << 20) + (1u << 18) + (6u << 19));
    float* out = (float*)d_out;

    hipFuncSetAttribute((const void*)k_main,
                        hipFuncAttributeMaxDynamicSharedMemorySize, LDS_TOTAL);

    hipLaunchKernelGGL(k_colmax, dim3(1024), dim3(256), 0, stream, W_rec, t1a);
    hipLaunchKernelGGL(k_packq, dim3(4096), dim3(256), 0, stream, W_rec, t1a, WrQ);
    hipLaunchKernelGGL(k_pack3, dim3(3072), dim3(256), 0, stream, W_in, Wi1, Wi2, Wi3, 768);
    hipLaunchKernelGGL(k_main, dim3(128), dim3(1024), LDS_TOTAL, stream,
                       fused, Wi1, Wi2, Wi3, b_in, WrQ, t1a, b_rec,
                       rdec, rfrq, W_out, b_out, out);
}

// Round 12
// 894.551 us; speedup vs baseline: 7.6597x; 4.3421x over previous
//
#include <hip/hip_runtime.h>

typedef __attribute__((ext_vector_type(4))) float f32x4;
typedef __attribute__((ext_vector_type(4))) int   i32x4;
typedef __attribute__((ext_vector_type(8))) short s16x8;

#define MFMA16(a, b, c)  __builtin_amdgcn_mfma_f32_16x16x32_bf16((a), (b), (c), 0, 0, 0)
#define MFMAI8(a, b, c)  __builtin_amdgcn_mfma_i32_16x16x64_i8((a), (b), (c), 0, 0, 0)

#define QINV (1.0f / 252.0f)

// global->LDS async copy, 16B/lane; LDS dest wave-uniform base (+lane*16 implicit).
typedef __attribute__((address_space(3))) unsigned int lds_uint;
typedef const __attribute__((address_space(1))) unsigned int glob_uint;
__device__ __forceinline__ void glds16(const void* g, void* l) {
    __builtin_amdgcn_global_load_lds((glob_uint*)g, (lds_uint*)l, 16, 0, 0);
}

// ---------- bf16 helpers (RNE) ----------
__device__ inline unsigned short f2bf(float f) {
    unsigned int u = __float_as_uint(f);
    return (unsigned short)((u + 0x7FFFu + ((u >> 16) & 1u)) >> 16);
}
__device__ inline float bf2f(unsigned short b) {
    return __uint_as_float(((unsigned int)b) << 16);
}

// ---------- pack W [K][1024] f32 -> THREE bf16 levels (W_in path) ----------
__global__ __launch_bounds__(256) void k_pack3(const float* __restrict__ W,
                                               unsigned short* __restrict__ L1,
                                               unsigned short* __restrict__ L2,
                                               unsigned short* __restrict__ L3,
                                               int K) {
    int idx = blockIdx.x * 256 + threadIdx.x;
    if (idx >= K * 1024) return;
    int k = idx >> 10;
    int n = idx & 1023;
    float x = W[idx];
    unsigned short h1 = f2bf(x);  float r1 = x - bf2f(h1);
    unsigned short h2 = f2bf(r1); float r2 = r1 - bf2f(h2);
    unsigned short h3 = f2bf(r2);
    size_t o = ((size_t)(k >> 5) << 15) + ((size_t)n << 5) + (k & 31);
    L1[o] = h1; L2[o] = h2; L3[o] = h3;
}

// ---------- per-column max|W_rec| -> t1[n] = max/126 ----------
__global__ __launch_bounds__(256) void k_colmax(const float* __restrict__ W,
                                                float* __restrict__ t1) {
    __shared__ float red[256];
    int n = blockIdx.x;
    float m = 0.f;
    for (int k = threadIdx.x; k < 1024; k += 256)
        m = fmaxf(m, fabsf(W[(size_t)k * 1024 + n]));
    red[threadIdx.x] = m;
    __syncthreads();
    for (int s = 128; s > 0; s >>= 1) {
        if (threadIdx.x < s) red[threadIdx.x] = fmaxf(red[threadIdx.x], red[threadIdx.x + s]);
        __syncthreads();
    }
    if (threadIdx.x == 0) t1[n] = fmaxf(red[0], 1e-30f) * (1.0f / 126.0f);
}

// ---------- pack W_rec -> 3 i8 digits as MFMA-ready 1KB frags ----------
// frag id = (kt*64 + cg)*3 + lvl ; within frag, byte = lane*16 + j where
// lane = ((k>>4)&3)*16 + (n&15), j = k&15  (exact mfma_i32_16x16x64_i8 B layout,
// cols cg*16..cg*16+15, k = kt*64..+63). Every frag is 1KB CONTIGUOUS.
__global__ __launch_bounds__(256) void k_packq(const float* __restrict__ W,
                                               const float* __restrict__ t1a,
                                               signed char* __restrict__ Q) {
    int idx = blockIdx.x * 256 + threadIdx.x;   // k*1024 + n
    int k = idx >> 10;
    int n = idx & 1023;
    float x = W[idx];
    float T1 = t1a[n];
    float T2 = T1 * QINV;
    float T3 = T2 * QINV;
    float q1 = rintf(x / T1);  float r1 = fmaf(-q1, T1, x);
    float q2 = rintf(r1 / T2); float r2 = fmaf(-q2, T2, r1);
    float q3 = rintf(r2 / T3);
    int kt = k >> 6, cg = n >> 4;
    int lane = (((k >> 4) & 3) << 4) | (n & 15);
    size_t base = ((size_t)((kt * 64 + cg) * 3)) << 10;
    size_t lj = (size_t)lane * 16 + (k & 15);
    Q[base + lj]        = (signed char)(int)q1;
    Q[base + 1024 + lj] = (signed char)(int)q2;
    Q[base + 2048 + lj] = (signed char)(int)q3;
}

// ---------- main: 128 blocks x 16 rows, 512 thr (8 waves, 2 waves/SIMD) ----------
// Per step: two col-passes (g=0: cols 0-511, g=1: 512-1023) REUSING acc[4][3]
// (48 AGPR). B-frags stream through a wave-private 12-slot x 1KB LDS ring via
// global_load_lds (zero VGPR cost, contiguous 1KB per issue), counted
// vmcnt(11); slot = nt*3+lvl is kt-invariant so the stream self-aligns.
#define FSTR 770
#define LDS_SPK0   0        // i8 [16][1024] XOR-swizzled, buf0
#define LDS_SPK1   16384    // buf1
#define LDS_DEC    32768    // f32[1024]
#define LDS_FRQ    36864
#define LDS_T1     40960
#define LDS_RING   45056    // 8 waves x 12288 B (12 slots x 1 KB) -> 143360
#define LDS_FUSED  32768    // f32 [16][770] (phases A/B only; dies before params)
#define LDS_PLDS   45056    // f32 [16][1028] (phase D; ring dead)
#define LDS_TOTAL  143360

// macros reference locals: ring, lane16, Af, acc, inext (inext has NO lane16;
// the macro adds it exactly once — R11's bug was a double lane16 here)
#define RING_ITER(nt, lvl)                                                     \
    {                                                                          \
        asm volatile("s_waitcnt vmcnt(11)" ::: "memory");                      \
        __builtin_amdgcn_sched_barrier(0);                                     \
        i32x4 Bv = *(const i32x4*)(ring + ((nt)*3 + (lvl)) * 1024 + lane16);   \
        acc[nt][lvl] = MFMAI8(Af, Bv, acc[nt][lvl]);                           \
        __builtin_amdgcn_sched_barrier(0);                                     \
        glds16(inext + ((nt)*3 + (lvl)) * 1024 + lane16,                       \
               ring + ((nt)*3 + (lvl)) * 1024);                                \
    }
#define RING_LAST(nt, lvl, N)                                                  \
    {                                                                          \
        asm volatile("s_waitcnt vmcnt(" #N ")" ::: "memory");                  \
        __builtin_amdgcn_sched_barrier(0);                                     \
        i32x4 Bv = *(const i32x4*)(ring + ((nt)*3 + (lvl)) * 1024 + lane16);   \
        acc[nt][lvl] = MFMAI8(Af, Bv, acc[nt][lvl]);                           \
    }

__global__ __launch_bounds__(512, 2) void k_main(const float* __restrict__ fused,
                                                 const unsigned short* __restrict__ Wi1,
                                                 const unsigned short* __restrict__ Wi2,
                                                 const unsigned short* __restrict__ Wi3,
                                                 const float* __restrict__ b_in,
                                                 const signed char* __restrict__ WrQ,
                                                 const float* __restrict__ t1a,
                                                 const float* __restrict__ b_rec,
                                                 const float* __restrict__ rdec,
                                                 const float* __restrict__ rfrq,
                                                 const float* __restrict__ W_out,
                                                 const float* __restrict__ b_out,
                                                 float* __restrict__ out) {
    extern __shared__ __align__(16) char smem[];
    const int tid = threadIdx.x;
    const int w = tid >> 6, lane = tid & 63;
    const int llo = lane & 15, lhi = lane >> 4;
    const int r0 = blockIdx.x * 16;
    const int lane16 = lane * 16;

    // ---- phase A: stage fused[r0:r0+16][0:768] -> LDS ----
    float* fl = (float*)(smem + LDS_FUSED);
    for (int i = tid; i < 16 * 768; i += 512) {
        int rr = i / 768, cc = i - rr * 768;
        fl[rr * FSTR + cc] = fused[(size_t)(r0 + rr) * 768 + cc];
    }
    __syncthreads();

    // ---- phase B: base = fused @ W_in + b_in (3x3-level bf16, 6 passes) ----
    f32x4 bacc[2][4] = {};
    for (int kt = 0; kt < 24; ++kt) {
        const float* ap = fl + llo * FSTR + kt * 32 + lhi * 8;
        s16x8 a1v, a2v, a3v;
#pragma unroll
        for (int j = 0; j < 8; ++j) {
            float x = ap[j];
            unsigned short h1 = f2bf(x);  float r1 = x - bf2f(h1);
            unsigned short h2 = f2bf(r1); float r2 = r1 - bf2f(h2);
            a1v[j] = (short)h1; a2v[j] = (short)h2; a3v[j] = (short)f2bf(r2);
        }
#pragma unroll
        for (int g = 0; g < 2; ++g) {
#pragma unroll
            for (int nt = 0; nt < 4; ++nt) {
                int c = g * 512 + w * 64 + nt * 16 + llo;
                size_t boff = ((size_t)(kt * 1024 + c) << 5) + lhi * 8;
                s16x8 b1 = *(const s16x8*)&Wi1[boff];
                s16x8 b2 = *(const s16x8*)&Wi2[boff];
                s16x8 b3 = *(const s16x8*)&Wi3[boff];
                bacc[g][nt] = MFMA16(a1v, b1, bacc[g][nt]);
                bacc[g][nt] = MFMA16(a1v, b2, bacc[g][nt]);
                bacc[g][nt] = MFMA16(a2v, b1, bacc[g][nt]);
                bacc[g][nt] = MFMA16(a2v, b2, bacc[g][nt]);
                bacc[g][nt] = MFMA16(a1v, b3, bacc[g][nt]);
                bacc[g][nt] = MFMA16(a3v, b1, bacc[g][nt]);
            }
        }
    }
    __syncthreads();   // fused dead; region becomes params

    // ---- params ----
    float* ldsDec = (float*)(smem + LDS_DEC);
    float* ldsFrq = (float*)(smem + LDS_FRQ);
    float* ldsT1  = (float*)(smem + LDS_T1);
    for (int c = tid; c < 1024; c += 512) {
        ldsDec[c] = (float)(0.55 + 0.4 / (1.0 + exp(-(double)rdec[c])));
        ldsFrq[c] = (float)(0.10 + 0.9 / (1.0 + exp(-(double)rfrq[c])));
        ldsT1[c]  = t1a[c];
    }

    // ---- base2 in regs; inline t=0; spikes(0) -> SPK0 ----
    float base2[2][4][4];
    float mem[2][4][4], res[2][4][4];
    unsigned int pooled_pk[2][4] = {};
#pragma unroll
    for (int g = 0; g < 2; ++g) {
#pragma unroll
        for (int nt = 0; nt < 4; ++nt) {
            int c = g * 512 + w * 64 + nt * 16 + llo;
            float bb = b_in[c];
            float brv = b_rec[c];
#pragma unroll
            for (int fr = 0; fr < 4; ++fr) {
                int row = lhi * 4 + fr;
                float b0 = __fadd_rn(bacc[g][nt][fr], bb);
                base2[g][nt][fr] = __fadd_rn(b0, brv);
                float m_ = __fadd_rn(0.f, b0);
                int s = (m_ > 1.0f) ? 1 : 0;
                res[g][nt][fr] = 0.f;
                mem[g][nt][fr] = __fadd_rn(m_, -(float)s);
                pooled_pk[g][nt] += (unsigned int)s << (8 * fr);
                *(unsigned char*)(smem + LDS_SPK0 + ((row * 1024 + c) ^ ((row & 7) << 4))) =
                    (unsigned char)s;
            }
        }
    }
    __syncthreads();

    // ---- phase C: steps 1..31 ----
    const int ax = (llo & 7) << 4;
    char* ring = smem + LDS_RING + w * 12288;
    for (int t = 1; t < 32; ++t) {
        const char* ab = smem + ((t - 1) & 1) * 16384 + llo * 1024;
        char* wb = smem + (t & 1) * 16384;

#pragma unroll
        for (int g = 0; g < 2; ++g) {
            i32x4 acc[4][3] = {};
            if (g == 0) {
                // prologue: issue 12 frags of (g0, kt0); source = frag base + lane16
                const signed char* ib =
                    WrQ + (((size_t)(w * 4) * 3) << 10) + lane16;
#pragma unroll
                for (int s = 0; s < 12; ++s)
                    glds16(ib + s * 1024, ring + s * 1024);
            }
            for (int kt = 0; kt < 16; ++kt) {
                i32x4 Af = *(const i32x4*)(ab + ((kt * 64 + lhi * 16) ^ ax));
                if (kt < 15 || g == 0) {
                    // next-kt frag base, NO lane16 (macro adds it once)
                    const int nkt = (kt < 15) ? kt + 1 : 0;
                    const int ng  = (kt < 15) ? g : 1;
                    const signed char* inext =
                        WrQ + (((size_t)(nkt * 64 + ng * 32 + w * 4) * 3) << 10);
                    RING_ITER(0, 0) RING_ITER(0, 1) RING_ITER(0, 2)
                    RING_ITER(1, 0) RING_ITER(1, 1) RING_ITER(1, 2)
                    RING_ITER(2, 0) RING_ITER(2, 1) RING_ITER(2, 2)
                    RING_ITER(3, 0) RING_ITER(3, 1) RING_ITER(3, 2)
                } else {
                    RING_LAST(0, 0, 11) RING_LAST(0, 1, 10) RING_LAST(0, 2, 9)
                    RING_LAST(1, 0, 8)  RING_LAST(1, 1, 7)  RING_LAST(1, 2, 6)
                    RING_LAST(2, 0, 5)  RING_LAST(2, 1, 4)  RING_LAST(2, 2, 3)
                    RING_LAST(3, 0, 2)  RING_LAST(3, 1, 1)  RING_LAST(3, 2, 0)
                }
            }
            // state update, group g (exact np op order)
#pragma unroll
            for (int nt = 0; nt < 4; ++nt) {
                int c = g * 512 + w * 64 + nt * 16 + llo;
                float dcc = ldsDec[c], fqc = ldsFrq[c], t1c = ldsT1[c];
#pragma unroll
                for (int fr = 0; fr < 4; ++fr) {
                    int row = lhi * 4 + fr;
                    float s3 = (float)acc[nt][2][fr];
                    float s2 = fmaf(s3, QINV, (float)acc[nt][1][fr]);
                    float rec = __fmul_rn(fmaf(s2, QINV, (float)acc[nt][0][fr]), t1c);
                    float drive = __fadd_rn(base2[g][nt][fr], rec);
                    float rnew = __fadd_rn(__fmul_rn(dcc, res[g][nt][fr]),
                                           __fmul_rn(fqc, mem[g][nt][fr]));
                    float tt = __fadd_rn(__fmul_rn(dcc, mem[g][nt][fr]), drive);
                    float m_ = __fadd_rn(tt, -rnew);
                    int s = (m_ > 1.0f) ? 1 : 0;
                    res[g][nt][fr] = rnew;
                    mem[g][nt][fr] = __fadd_rn(m_, -(float)s);
                    pooled_pk[g][nt] += (unsigned int)s << (8 * fr);
                    *(unsigned char*)(wb + ((row * 1024 + c) ^ ((row & 7) << 4))) =
                        (unsigned char)s;
                }
            }
        }
        __syncthreads();
    }

    // ---- phase D: pooled/32 -> LDS (ring region, dead), f64 dot W_out ----
    float* plds = (float*)(smem + LDS_PLDS);
#pragma unroll
    for (int g = 0; g < 2; ++g)
#pragma unroll
        for (int nt = 0; nt < 4; ++nt) {
            int c = g * 512 + w * 64 + nt * 16 + llo;
#pragma unroll
            for (int fr = 0; fr < 4; ++fr)
                plds[(lhi * 4 + fr) * 1028 + c] =
                    (float)((pooled_pk[g][nt] >> (8 * fr)) & 255u) * 0.03125f;
        }
    __syncthreads();
    if (tid < 256) {
        int row = tid >> 4, o = tid & 15;
        double s = 0.0;
        for (int h = 0; h < 1024; ++h)
            s += (double)plds[row * 1028 + h] * (double)W_out[h * 16 + o];
        out[(size_t)(r0 + row) * 16 + o] = __fadd_rn((float)s, b_out[o]);
    }
}

extern "C" void kernel_launch(void* const* d_in, const int* in_sizes, int n_in,
                              void* d_out, int out_size, void* d_ws, size_t ws_size,
                              hipStream_t stream) {
    const float* fused = (const float*)d_in[0];
    const float* W_in  = (const float*)d_in[1];
    const float* b_in  = (const float*)d_in[2];
    const float* W_rec = (const float*)d_in[3];
    const float* b_rec = (const float*)d_in[4];
    const float* W_out = (const float*)d_in[5];
    const float* b_out = (const float*)d_in[6];
    const float* rdec  = (const float*)d_in[7];
    const float* rfrq  = (const float*)d_in[8];

    // ws: WrQ 3MB | t1 4KB | Wi1/2/3 4.5MB  (total ~7.75MB)
    char* ws = (char*)d_ws;
    signed char*    WrQ = (signed char*)(ws);
    float*          t1a = (float*)(ws + (3u << 20));
    unsigned short* Wi1 = (unsigned short*)(ws + (3u << 20) + (1u << 18));
    unsigned short* Wi2 = (unsigned short*)(ws + (3u << 20) + (1u << 18) + (3u << 19));
    unsigned short* Wi3 = (unsigned short*)(ws + (3u << 20) + (1u << 18) + (6u << 19));
    float* out = (float*)d_out;

    hipFuncSetAttribute((const void*)k_main,
                        hipFuncAttributeMaxDynamicSharedMemorySize, LDS_TOTAL);

    hipLaunchKernelGGL(k_colmax, dim3(1024), dim3(256), 0, stream, W_rec, t1a);
    hipLaunchKernelGGL(k_packq, dim3(4096), dim3(256), 0, stream, W_rec, t1a, WrQ);
    hipLaunchKernelGGL(k_pack3, dim3(3072), dim3(256), 0, stream, W_in, Wi1, Wi2, Wi3, 768);
    hipLaunchKernelGGL(k_main, dim3(128), dim3(512), LDS_TOTAL, stream,
                       fused, Wi1, Wi2, Wi3, b_in, WrQ, t1a, b_rec,
                       rdec, rfrq, W_out, b_out, out);
}